// Round 4
// baseline (496.381 us; speedup 1.0000x reference)
//
#include <hip/hip_runtime.h>
#include <hip/hip_bf16.h>

// AngularMarginLoss: B=2048, D=256, C=100000
// loss = -mean_b( num_b - log(exp(num_b) + sum_{c!=t_b} exp(30*cos_bc) + 1e-6) )
// num_b = 30*cos(acos(clip(cos_bt)) + 0.2)
//
// Round-4: barrier-free, LDS-free k_main at 2 waves/SIMD (reg-capped by
// 128-VGPR persistent afrag). 1564 blocks = 391 col-blocks x 4 sample
// quarters; the 4 waves of a block share the same 512 samples (B-loads hit
// L1) and own disjoint 64-col A-sets. B-fragments go global->register with
// unroll-2 ping-pong prefetch (issue ~800 cyc before use). W is
// pre-normalized to bf16 once by k_wnorm (removes the 800MB 2-pass prologue).

static constexpr int Bn = 2048;
static constexpr int Dn = 256;
static constexpr int Cn = 100000;
static constexpr int NCBLK  = 391;                  // col-blocks of 256 cols
static constexpr int CPAD   = NCBLK * 256;          // 100096
static constexpr int SLICES = NCBLK * 4;            // 64-col slices = 1564
static constexpr float OOB_COLS = (float)(CPAD - Cn);   // 96
static constexpr int QS = 512;                      // samples per quarter

#define SCALE_F 30.0f
#define MARGIN_F 0.2f
#define EPS_F 1e-6f

typedef __attribute__((ext_vector_type(8))) short bf16x8;   // 8 bf16 = 4 VGPRs
typedef __attribute__((ext_vector_type(4))) float f32x4;

__device__ __forceinline__ short f2bf_rne(float x) {
    union { float f; unsigned int u; } v; v.f = x;
    unsigned int r = v.u + 0x7fffu + ((v.u >> 16) & 1u);
    return (short)(r >> 16);
}

// ---- kernel 1: emb fp32 -> bf16 (row-major, 2048x256) ----
__global__ __launch_bounds__(256) void k_emb2bf(const float* __restrict__ emb,
                                                short* __restrict__ out) {
    int i = (blockIdx.x * 256 + threadIdx.x) * 4;   // 512 blocks covers 524288 exactly
    float4 x = *(const float4*)(emb + i);
    short4 o;
    o.x = f2bf_rne(x.x); o.y = f2bf_rne(x.y);
    o.z = f2bf_rne(x.z); o.w = f2bf_rne(x.w);
    *(short4*)(out + i) = o;
}

// ---- kernel 1b: W -> row-normalized bf16 (CPAD rows; tail rows = 0) ----
__global__ __launch_bounds__(256) void k_wnorm(const float* __restrict__ W,
                                               short* __restrict__ Wn) {
    const int r    = blockIdx.x * 4 + (threadIdx.x >> 6);   // 25024 blocks -> CPAD rows
    const int lane = threadIdx.x & 63;
    float4 x = {0.f, 0.f, 0.f, 0.f};
    if (r < Cn) x = *(const float4*)(W + (size_t)r * Dn + lane * 4);
    float ss = x.x * x.x + x.y * x.y + x.z * x.z + x.w * x.w;
#pragma unroll
    for (int o = 1; o < 64; o <<= 1) ss += __shfl_xor(ss, o);
    const float rn = 1.0f / fmaxf(sqrtf(ss), 1e-12f);   // r>=Cn: x=0 -> stores 0
    short4 o;
    o.x = f2bf_rne(x.x * rn); o.y = f2bf_rne(x.y * rn);
    o.z = f2bf_rne(x.z * rn); o.w = f2bf_rne(x.w * rn);
    *(short4*)(Wn + (size_t)r * Dn + lane * 4) = o;
}

// ---- kernel 2: main fused GEMM + exp row-sum (no LDS, no barriers) ----
template <bool USE_WN>
__global__ __launch_bounds__(256, 2) void k_main(const float* __restrict__ W,
                                                 const short* __restrict__ Wn,
                                                 const short* __restrict__ embbf,
                                                 float* __restrict__ partial) {
    const int tid  = threadIdx.x;
    const int wave = tid >> 6;
    const int lane = tid & 63;
    const int q    = lane >> 4;   // quad 0..3
    const int cr   = lane & 15;

    const int cblk    = blockIdx.x >> 2;       // 0..390
    const int quarter = blockIdx.x & 3;        // 0..3
    const int cbase   = cblk * 256 + wave * 64;
    const int sbase   = quarter * QS;

    // ---- prologue: persistent A-fragments for 4 col-tiles (128 VGPRs) ----
    // A layout (16x16x32): lane holds A[m=cr][k=q*8+j] per 32-wide k-step.
    bf16x8 afrag[4][8];
    if (USE_WN) {
#pragma unroll
        for (int ct = 0; ct < 4; ++ct) {
            const short* wr = Wn + (size_t)(cbase + ct * 16 + cr) * Dn + q * 8;
#pragma unroll
            for (int ks = 0; ks < 8; ++ks)
                afrag[ct][ks] = *(const bf16x8*)(wr + ks * 32);
        }
    } else {
        // fallback: 2-pass normalize from fp32 W (no Wn scratch available)
#pragma unroll
        for (int ct = 0; ct < 4; ++ct) {
            const int c = cbase + ct * 16 + cr;
            const float* wr = W + (size_t)c * Dn;
            float ss = 0.0f;
            if (c < Cn) {
#pragma unroll
                for (int ks = 0; ks < 8; ++ks) {
                    float4 x0 = *(const float4*)(wr + ks * 32 + q * 8);
                    float4 x1 = *(const float4*)(wr + ks * 32 + q * 8 + 4);
                    ss += x0.x * x0.x + x0.y * x0.y + x0.z * x0.z + x0.w * x0.w;
                    ss += x1.x * x1.x + x1.y * x1.y + x1.z * x1.z + x1.w * x1.w;
                }
            }
            ss += __shfl_xor(ss, 16);
            ss += __shfl_xor(ss, 32);
            const float rn = 1.0f / fmaxf(sqrtf(ss), 1e-12f);
#pragma unroll
            for (int ks = 0; ks < 8; ++ks) {
                bf16x8 a = {0, 0, 0, 0, 0, 0, 0, 0};
                if (c < Cn) {
                    float4 x0 = *(const float4*)(wr + ks * 32 + q * 8);
                    float4 x1 = *(const float4*)(wr + ks * 32 + q * 8 + 4);
                    a[0] = f2bf_rne(x0.x * rn); a[1] = f2bf_rne(x0.y * rn);
                    a[2] = f2bf_rne(x0.z * rn); a[3] = f2bf_rne(x0.w * rn);
                    a[4] = f2bf_rne(x1.x * rn); a[5] = f2bf_rne(x1.y * rn);
                    a[6] = f2bf_rne(x1.z * rn); a[7] = f2bf_rne(x1.w * rn);
                }
                afrag[ct][ks] = a;
            }
        }
    }

    float* pout = partial + (size_t)(cblk * 4 + wave) * Bn + sbase;

    // B layout per 16-sample tile: lane holds B[k=q*8+j][n=cr] = emb[sbase+it*16+cr][k]
    auto load_b = [&](bf16x8* bf, int it) {
        int row = sbase + it * 16 + cr;
        row = row < Bn ? row : Bn - 1;          // prefetch-past-end clamp
        const short* p = embbf + (size_t)row * Dn + q * 8;
#pragma unroll
        for (int ks = 0; ks < 8; ++ks) bf[ks] = *(const bf16x8*)(p + ks * 32);
    };

    auto compute = [&](const bf16x8* bf, int it) {
        f32x4 acc0 = {0.f, 0.f, 0.f, 0.f};
        f32x4 acc1 = {0.f, 0.f, 0.f, 0.f};
        f32x4 acc2 = {0.f, 0.f, 0.f, 0.f};
        f32x4 acc3 = {0.f, 0.f, 0.f, 0.f};
#pragma unroll
        for (int ks = 0; ks < 8; ++ks) {
            acc0 = __builtin_amdgcn_mfma_f32_16x16x32_bf16(afrag[0][ks], bf[ks], acc0, 0, 0, 0);
            acc1 = __builtin_amdgcn_mfma_f32_16x16x32_bf16(afrag[1][ks], bf[ks], acc1, 0, 0, 0);
            acc2 = __builtin_amdgcn_mfma_f32_16x16x32_bf16(afrag[2][ks], bf[ks], acc2, 0, 0, 0);
            acc3 = __builtin_amdgcn_mfma_f32_16x16x32_bf16(afrag[3][ks], bf[ks], acc3, 0, 0, 0);
        }
        // D layout: col=lane&15=sample, row=q*4+reg=class. Sum exp over classes.
        float s = 0.0f;
#pragma unroll
        for (int r = 0; r < 4; ++r) {
            s += __expf(SCALE_F * fminf(fmaxf(acc0[r], -1.f), 1.f));
            s += __expf(SCALE_F * fminf(fmaxf(acc1[r], -1.f), 1.f));
            s += __expf(SCALE_F * fminf(fmaxf(acc2[r], -1.f), 1.f));
            s += __expf(SCALE_F * fminf(fmaxf(acc3[r], -1.f), 1.f));
        }
        s += __shfl_xor(s, 16);
        s += __shfl_xor(s, 32);
        if (lane < 16) pout[it * 16 + cr] = s;   // coalesced 64B store
    };

    bf16x8 b0[8], b1[8];
    load_b(b0, 0);
    for (int it = 0; it < QS / 16; it += 2) {
        load_b(b1, it + 1);     // issue ~1 body ahead of use
        compute(b0, it);
        load_b(b0, it + 2);
        compute(b1, it + 1);
    }
}

// ---- kernel 3: per-sample target cosine (fp32), wave-per-sample ----
__global__ __launch_bounds__(256) void k_target(const float* __restrict__ emb,
                                                const float* __restrict__ W,
                                                const int* __restrict__ tgt,
                                                float* __restrict__ numv,
                                                float* __restrict__ etv) {
    const int b    = blockIdx.x * 4 + (threadIdx.x >> 6);
    const int lane = threadIdx.x & 63;
    const int t    = tgt[b];
    float4 x = *(const float4*)(W + (size_t)t * Dn + lane * 4);
    float4 e = *(const float4*)(emb + b * Dn + lane * 4);
    float dot = x.x * e.x + x.y * e.y + x.z * e.z + x.w * e.w;
    float ss  = x.x * x.x + x.y * x.y + x.z * x.z + x.w * x.w;
#pragma unroll
    for (int o = 1; o < 64; o <<= 1) {
        dot += __shfl_xor(dot, o);
        ss  += __shfl_xor(ss, o);
    }
    if (lane == 0) {
        float cosv = dot / fmaxf(sqrtf(ss), 1e-12f);
        cosv = fminf(fmaxf(cosv, -1.f), 1.f);
        const float num = SCALE_F * cosf(acosf(cosv) + MARGIN_F);
        numv[b] = num;
        etv[b]  = __expf(SCALE_F * cosv);
    }
}

// ---- kernel 4: reduce partials over slices ----
__global__ __launch_bounds__(256) void k_rowsum(const float* __restrict__ partial,
                                                float* __restrict__ rowsum) {
    const int b = blockIdx.x * 256 + threadIdx.x;   // 8 blocks x 256
    float acc = 0.0f;
    int s = 0;
    for (; s + 4 <= SLICES; s += 4) {
        acc += partial[(size_t)(s + 0) * Bn + b];
        acc += partial[(size_t)(s + 1) * Bn + b];
        acc += partial[(size_t)(s + 2) * Bn + b];
        acc += partial[(size_t)(s + 3) * Bn + b];
    }
    for (; s < SLICES; ++s) acc += partial[(size_t)s * Bn + b];
    rowsum[b] = acc;
}

// ---- kernel 5: final loss reduction ----
__global__ __launch_bounds__(256) void k_loss(const float* __restrict__ numv,
                                              const float* __restrict__ etv,
                                              const float* __restrict__ rowsum,
                                              float* __restrict__ out) {
    float acc = 0.0f;
    for (int b = threadIdx.x; b < Bn; b += 256) {
        const float num  = numv[b];
        const float excl = rowsum[b] - OOB_COLS - etv[b];   // drop padding + target col
        const float denom = __expf(num) + excl;
        acc += num - logf(denom + EPS_F);
    }
#pragma unroll
    for (int o = 1; o < 64; o <<= 1) acc += __shfl_xor(acc, o);
    __shared__ float sa[4];
    const int wave = threadIdx.x >> 6, lane = threadIdx.x & 63;
    if (lane == 0) sa[wave] = acc;
    __syncthreads();
    if (threadIdx.x == 0) out[0] = -(sa[0] + sa[1] + sa[2] + sa[3]) / (float)Bn;
}

extern "C" void kernel_launch(void* const* d_in, const int* in_sizes, int n_in,
                              void* d_out, int out_size, void* d_ws, size_t ws_size,
                              hipStream_t stream) {
    const float* emb = (const float*)d_in[0];   // 2048*256
    const float* W   = (const float*)d_in[1];   // 100000*256
    const int*   tgt = (const int*)d_in[2];     // 2048
    float* out = (float*)d_out;

    char* ws = (char*)d_ws;
    short* embbf   = (short*)ws;                             // 1 MB
    float* partial = (float*)(ws + (1 << 20));               // 1564*2048*4 = 12.8 MB
    float* rowsum  = partial + (size_t)SLICES * Bn;          // 8 KB
    float* numv    = rowsum + Bn;                            // 8 KB
    float* etv     = numv + Bn;                              // 8 KB
    short* Wnorm   = (short*)(etv + Bn);                     // CPAD*256*2 = 51.25 MB

    const size_t need_full = (size_t)((char*)Wnorm - ws) + (size_t)CPAD * Dn * sizeof(short);
    const bool use_wn = ws_size >= need_full;   // ws_size constant -> same path every call

    k_emb2bf<<<512, 256, 0, stream>>>(emb, embbf);
    if (use_wn) {
        k_wnorm<<<CPAD / 4, 256, 0, stream>>>(W, Wnorm);
        k_main<true><<<NCBLK * 4, 256, 0, stream>>>(W, Wnorm, embbf, partial);
    } else {
        k_main<false><<<NCBLK * 4, 256, 0, stream>>>(W, Wnorm, embbf, partial);
    }
    k_target<<<Bn / 4, 256, 0, stream>>>(emb, W, tgt, numv, etv);
    k_rowsum<<<Bn / 256, 256, 0, stream>>>(partial, rowsum);
    k_loss<<<1, 256, 0, stream>>>(numv, etv, rowsum, out);
}

// Round 5
// 318.710 us; speedup vs baseline: 1.5575x; 1.5575x over previous
//
#include <hip/hip_runtime.h>
#include <hip/hip_bf16.h>

// AngularMarginLoss: B=2048, D=256, C=100000
// loss = -mean_b( num_b - log(exp(num_b) + sum_{c!=t_b} exp(30*cos_bc) + 1e-6) )
// num_b = 30*cos(acos(clip(cos_bt)) + 0.2)
//
// Round-5: k_main = 782 blocks x 4 waves; wave owns 32 cols (2 MFMA col-tiles,
// afrag = 64 VGPRs -> ~135 total -> 3 waves/SIMD, 3 blocks/CU). All 4 waves
// share 32-sample B tiles staged coalesced via global_load_lds(16B) with XOR
// chunk swizzle (conflict-free ds_read_b128). Double-buffered, 1 barrier/tile;
// with 3 independent blocks/CU the barrier drain is hidden. k_rowsum now 256
// blocks + atomicAdd (was 8 blocks = serial tail).

static constexpr int Bn = 2048;
static constexpr int Dn = 256;
static constexpr int Cn = 100000;
static constexpr int NCBLK  = 782;                  // col-blocks of 128 cols
static constexpr int CPAD   = NCBLK * 128;          // 100096
static constexpr int SLICES = NCBLK * 4;            // 32-col slices = 3128
static constexpr float OOB_COLS = (float)(CPAD - Cn);   // 96
static constexpr int NTILE = Bn / 32;               // 64 sample tiles per block

#define SCALE_F 30.0f
#define MARGIN_F 0.2f
#define EPS_F 1e-6f

typedef __attribute__((ext_vector_type(8))) short bf16x8;   // 8 bf16 = 4 VGPRs
typedef __attribute__((ext_vector_type(4))) float f32x4;
typedef __attribute__((address_space(3))) unsigned int lds_u32;
typedef const __attribute__((address_space(1))) unsigned int g_u32;

__device__ __forceinline__ void async_cp16(const void* g, void* lds) {
    __builtin_amdgcn_global_load_lds((g_u32*)g, (lds_u32*)lds, 16, 0, 0);
}

__device__ __forceinline__ short f2bf_rne(float x) {
    union { float f; unsigned int u; } v; v.f = x;
    unsigned int r = v.u + 0x7fffu + ((v.u >> 16) & 1u);
    return (short)(r >> 16);
}

// ---- kernel 1: emb fp32 -> bf16 (row-major, 2048x256) ----
__global__ __launch_bounds__(256) void k_emb2bf(const float* __restrict__ emb,
                                                short* __restrict__ out) {
    int i = (blockIdx.x * 256 + threadIdx.x) * 4;   // 512 blocks covers 524288 exactly
    float4 x = *(const float4*)(emb + i);
    short4 o;
    o.x = f2bf_rne(x.x); o.y = f2bf_rne(x.y);
    o.z = f2bf_rne(x.z); o.w = f2bf_rne(x.w);
    *(short4*)(out + i) = o;
}

// ---- kernel 1b: W -> row-normalized bf16 (CPAD rows; tail rows = 0) ----
__global__ __launch_bounds__(256) void k_wnorm(const float* __restrict__ W,
                                               short* __restrict__ Wn) {
    const int r    = blockIdx.x * 4 + (threadIdx.x >> 6);   // 25024 blocks
    const int lane = threadIdx.x & 63;
    float4 x = {0.f, 0.f, 0.f, 0.f};
    if (r < Cn) x = *(const float4*)(W + (size_t)r * Dn + lane * 4);
    float ss = x.x * x.x + x.y * x.y + x.z * x.z + x.w * x.w;
#pragma unroll
    for (int o = 1; o < 64; o <<= 1) ss += __shfl_xor(ss, o);
    const float rn = 1.0f / fmaxf(sqrtf(ss), 1e-12f);   // r>=Cn: x=0 -> stores 0
    short4 o;
    o.x = f2bf_rne(x.x * rn); o.y = f2bf_rne(x.y * rn);
    o.z = f2bf_rne(x.z * rn); o.w = f2bf_rne(x.w * rn);
    *(short4*)(Wn + (size_t)r * Dn + lane * 4) = o;
}

// ---- kernel 2: main fused GEMM + exp row-sum ----
template <bool USE_WN>
__global__ __launch_bounds__(256, 3) void k_main(const float* __restrict__ W,
                                                 const short* __restrict__ Wn,
                                                 const short* __restrict__ embbf,
                                                 float* __restrict__ partial) {
    __shared__ __align__(16) short stage[2 * 32 * 256];   // 2 x 16KB, swizzled

    const int tid  = threadIdx.x;
    const int wave = tid >> 6;
    const int lane = tid & 63;
    const int q    = lane >> 4;   // quad 0..3
    const int cr   = lane & 15;
    const int sw   = cr & 7;

    const int cblk  = blockIdx.x;
    const int cbase = cblk * 128 + wave * 32;

    // Staging: tile = 32 rows x 256 shorts, phys chunk p(r,c) = r*32 + (c ^ (r&7)).
    // global_load_lds: lane l writes phys chunk (l&31) of rows r0,r0+1 -> pick
    // the global source chunk (l&31)^(rl&7) so the logical layout lands swizzled.
    auto stage_tile = [&](int t, int buf) {
        short* dst = stage + buf * (32 * 256);
#pragma unroll
        for (int i = 0; i < 4; ++i) {
            const int r0 = wave * 8 + 2 * i;
            const int rl = r0 + (lane >> 5);
            const int c16 = (lane & 31) ^ (rl & 7);
            const short* g = embbf + (size_t)(t * 32 + rl) * Dn + c16 * 8;
            async_cp16(g, dst + r0 * 256);
        }
    };

    stage_tile(0, 0);

    // ---- prologue: persistent A-fragments for 2 col-tiles (64 VGPRs) ----
    // A layout (16x16x32): lane holds A[m=cr][k=q*8+j] per 32-wide k-step.
    bf16x8 afrag[2][8];
    if (USE_WN) {
#pragma unroll
        for (int ct = 0; ct < 2; ++ct) {
            const short* wr = Wn + (size_t)(cbase + ct * 16 + cr) * Dn + q * 8;
#pragma unroll
            for (int ks = 0; ks < 8; ++ks)
                afrag[ct][ks] = *(const bf16x8*)(wr + ks * 32);
        }
    } else {
        // fallback: 2-pass normalize from fp32 W (no Wn scratch available)
#pragma unroll
        for (int ct = 0; ct < 2; ++ct) {
            const int c = cbase + ct * 16 + cr;
            const float* wr = W + (size_t)c * Dn;
            float ss = 0.0f;
            if (c < Cn) {
#pragma unroll
                for (int ks = 0; ks < 8; ++ks) {
                    float4 x0 = *(const float4*)(wr + ks * 32 + q * 8);
                    float4 x1 = *(const float4*)(wr + ks * 32 + q * 8 + 4);
                    ss += x0.x * x0.x + x0.y * x0.y + x0.z * x0.z + x0.w * x0.w;
                    ss += x1.x * x1.x + x1.y * x1.y + x1.z * x1.z + x1.w * x1.w;
                }
            }
            ss += __shfl_xor(ss, 16);
            ss += __shfl_xor(ss, 32);
            const float rn = 1.0f / fmaxf(sqrtf(ss), 1e-12f);
#pragma unroll
            for (int ks = 0; ks < 8; ++ks) {
                bf16x8 a = {0, 0, 0, 0, 0, 0, 0, 0};
                if (c < Cn) {
                    float4 x0 = *(const float4*)(wr + ks * 32 + q * 8);
                    float4 x1 = *(const float4*)(wr + ks * 32 + q * 8 + 4);
                    a[0] = f2bf_rne(x0.x * rn); a[1] = f2bf_rne(x0.y * rn);
                    a[2] = f2bf_rne(x0.z * rn); a[3] = f2bf_rne(x0.w * rn);
                    a[4] = f2bf_rne(x1.x * rn); a[5] = f2bf_rne(x1.y * rn);
                    a[6] = f2bf_rne(x1.z * rn); a[7] = f2bf_rne(x1.w * rn);
                }
                afrag[ct][ks] = a;
            }
        }
    }

    __syncthreads();   // tile 0 staged

    float* pout = partial + (size_t)(cblk * 4 + wave) * Bn;

    for (int it = 0; it < NTILE; ++it) {
        const int buf = it & 1;
        if (it + 1 < NTILE) stage_tile(it + 1, buf ^ 1);   // prefetch next

        const short* sb = stage + buf * (32 * 256);
#pragma unroll
        for (int st = 0; st < 2; ++st) {
            // B layout: lane holds B[k=q*8+j][n=cr] = emb[row][k]; row=st*16+cr.
            // Logical chunk (4ks+q) of the row sits at phys (4ks+q)^(cr&7).
            const short* rowp = sb + (st * 16 + cr) * 256;
            bf16x8 bfrag[8];
#pragma unroll
            for (int ks = 0; ks < 8; ++ks)
                bfrag[ks] = *(const bf16x8*)(rowp + ((((ks << 2) | q) ^ sw) << 3));

            f32x4 acc0 = {0.f, 0.f, 0.f, 0.f};
            f32x4 acc1 = {0.f, 0.f, 0.f, 0.f};
#pragma unroll
            for (int ks = 0; ks < 8; ++ks) {
                acc0 = __builtin_amdgcn_mfma_f32_16x16x32_bf16(afrag[0][ks], bfrag[ks], acc0, 0, 0, 0);
                acc1 = __builtin_amdgcn_mfma_f32_16x16x32_bf16(afrag[1][ks], bfrag[ks], acc1, 0, 0, 0);
            }

            // D layout: col=lane&15=sample, row=q*4+reg=class. Sum exp over classes.
            float s = 0.0f;
#pragma unroll
            for (int r = 0; r < 4; ++r) {
                s += __expf(SCALE_F * fminf(fmaxf(acc0[r], -1.f), 1.f));
                s += __expf(SCALE_F * fminf(fmaxf(acc1[r], -1.f), 1.f));
            }
            s += __shfl_xor(s, 16);
            s += __shfl_xor(s, 32);
            if (lane < 16) pout[it * 32 + st * 16 + cr] = s;   // coalesced 64B
        }
        __syncthreads();   // drains prefetch, fences buffer reuse
    }
}

// ---- kernel 3: per-sample target cosine (fp32), wave-per-sample ----
__global__ __launch_bounds__(256) void k_target(const float* __restrict__ emb,
                                                const float* __restrict__ W,
                                                const int* __restrict__ tgt,
                                                float* __restrict__ numv,
                                                float* __restrict__ etv) {
    const int b    = blockIdx.x * 4 + (threadIdx.x >> 6);
    const int lane = threadIdx.x & 63;
    const int t    = tgt[b];
    float4 x = *(const float4*)(W + (size_t)t * Dn + lane * 4);
    float4 e = *(const float4*)(emb + b * Dn + lane * 4);
    float dot = x.x * e.x + x.y * e.y + x.z * e.z + x.w * e.w;
    float ss  = x.x * x.x + x.y * x.y + x.z * x.z + x.w * x.w;
#pragma unroll
    for (int o = 1; o < 64; o <<= 1) {
        dot += __shfl_xor(dot, o);
        ss  += __shfl_xor(ss, o);
    }
    if (lane == 0) {
        float cosv = dot / fmaxf(sqrtf(ss), 1e-12f);
        cosv = fminf(fmaxf(cosv, -1.f), 1.f);
        const float num = SCALE_F * cosf(acosf(cosv) + MARGIN_F);
        numv[b] = num;
        etv[b]  = __expf(SCALE_F * cosv);
    }
}

// ---- kernel 4: reduce partials over slices (parallel over slice-chunks) ----
static constexpr int SCHUNK = 98;                      // ceil(3128/32)
__global__ __launch_bounds__(256) void k_rowsum(const float* __restrict__ partial,
                                                float* __restrict__ rowsum) {
    const int b  = blockIdx.x * 256 + threadIdx.x;     // gridDim.x = 8
    const int s0 = blockIdx.y * SCHUNK;                // gridDim.y = 32
    const int s1 = min(s0 + SCHUNK, SLICES);
    float acc = 0.0f;
    for (int s = s0; s < s1; ++s) acc += partial[(size_t)s * Bn + b];
    atomicAdd(&rowsum[b], acc);
}

// ---- kernel 5: final loss reduction ----
__global__ __launch_bounds__(256) void k_loss(const float* __restrict__ numv,
                                              const float* __restrict__ etv,
                                              const float* __restrict__ rowsum,
                                              float* __restrict__ out) {
    float acc = 0.0f;
    for (int b = threadIdx.x; b < Bn; b += 256) {
        const float num  = numv[b];
        const float excl = rowsum[b] - OOB_COLS - etv[b];   // drop padding + target col
        const float denom = __expf(num) + excl;
        acc += num - logf(denom + EPS_F);
    }
#pragma unroll
    for (int o = 1; o < 64; o <<= 1) acc += __shfl_xor(acc, o);
    __shared__ float sa[4];
    const int wave = threadIdx.x >> 6, lane = threadIdx.x & 63;
    if (lane == 0) sa[wave] = acc;
    __syncthreads();
    if (threadIdx.x == 0) out[0] = -(sa[0] + sa[1] + sa[2] + sa[3]) / (float)Bn;
}

extern "C" void kernel_launch(void* const* d_in, const int* in_sizes, int n_in,
                              void* d_out, int out_size, void* d_ws, size_t ws_size,
                              hipStream_t stream) {
    const float* emb = (const float*)d_in[0];   // 2048*256
    const float* W   = (const float*)d_in[1];   // 100000*256
    const int*   tgt = (const int*)d_in[2];     // 2048
    float* out = (float*)d_out;

    char* ws = (char*)d_ws;
    short* embbf   = (short*)ws;                             // 1 MB
    float* partial = (float*)(ws + (1 << 20));               // 3128*2048*4 = 25.6 MB
    float* rowsum  = partial + (size_t)SLICES * Bn;          // 8 KB
    float* numv    = rowsum + Bn;                            // 8 KB
    float* etv     = numv + Bn;                              // 8 KB
    short* Wnorm   = (short*)(etv + Bn);                     // CPAD*256*2 = 51.25 MB

    const size_t need_full = (size_t)((char*)Wnorm - ws) + (size_t)CPAD * Dn * sizeof(short);
    const bool use_wn = ws_size >= need_full;   // ws_size constant -> same path every call

    hipMemsetAsync(rowsum, 0, Bn * sizeof(float), stream);
    k_emb2bf<<<512, 256, 0, stream>>>(emb, embbf);
    if (use_wn) {
        k_wnorm<<<CPAD / 4, 256, 0, stream>>>(W, Wnorm);
        k_main<true><<<NCBLK, 256, 0, stream>>>(W, Wnorm, embbf, partial);
    } else {
        k_main<false><<<NCBLK, 256, 0, stream>>>(W, Wnorm, embbf, partial);
    }
    k_target<<<Bn / 4, 256, 0, stream>>>(emb, W, tgt, numv, etv);
    k_rowsum<<<dim3(Bn / 256, 32), 256, 0, stream>>>(partial, rowsum);
    k_loss<<<1, 256, 0, stream>>>(numv, etv, rowsum, out);
}